// Round 9
// baseline (88.455 us; speedup 1.0000x reference)
//
#include <hip/hip_runtime.h>

typedef float f32x4 __attribute__((ext_vector_type(4)));
typedef short bf16x8 __attribute__((ext_vector_type(8)));
typedef __bf16 bf16x2_t __attribute__((ext_vector_type(2)));
typedef unsigned int u32;
typedef unsigned long long u64;

__device__ __forceinline__ u32 pk2(float a, float b){
  bf16x2_t h; h[0] = (__bf16)a; h[1] = (__bf16)b;
  return __builtin_bit_cast(u32, h);
}
__device__ __forceinline__ unsigned short f2bf(float f){
  __bf16 h = (__bf16)f;
  return __builtin_bit_cast(unsigned short, h);
}
__device__ __forceinline__ float bf2f(unsigned short h){
  u32 u = ((u32)h) << 16;
  return __builtin_bit_cast(float, u);
}

// ws layout in ushort (bf16) units
#define WS_WOFT  98304u    // [512][64]  Wo_foldT[n][k] row-major
#define WS_QP    131072u   // [8192][64]  qp * 0.125*log2(e) folded
#define WS_KP    655360u   // [8192][64]
#define WS_VPT   1179648u  // [4][64][2048]  vp transposed per batch

#define QSCALE 0.18033688011112042f   // 0.125 * log2(e)

// B-fragment gather straight from fp32 W (row-major [512][64], L2-resident):
// fragment (kc, cg): lane l, elem j  ->  W[(kc*32 + (l>>4)*8 + j)*64 + cg*16 + (l&15)]
__device__ __forceinline__ bf16x8 wfrag(const float* __restrict__ W, int kc, int cg,
                                        int g, int ln){
  const float* p = W + (size_t)(kc*32 + g*8)*64 + cg*16 + ln;
  union { bf16x8 v8; u32 w[4]; } u;
  #pragma unroll
  for (int j = 0; j < 4; ++j)
    u.w[j] = pk2(p[(2*j)*64], p[(2*j+1)*64]);
  return u.v8;
}

// ---------------- K1: projection GEMMs + Wo fold (grid 256 x 4) -------------
__global__ __launch_bounds__(128) void k_proj(const float* __restrict__ q,
    const float* __restrict__ kmat, const float* __restrict__ v,
    const float* __restrict__ bq, const float* __restrict__ bk,
    const float* __restrict__ bv, const float* __restrict__ Wq,
    const float* __restrict__ Wk, const float* __restrict__ Wv,
    const float* __restrict__ Wo, unsigned short* __restrict__ wsu){
  const int which = blockIdx.y;
  if (which == 3){
    int r = blockIdx.x*128 + threadIdx.x;     // exactly 32768
    int n = r >> 6, k = r & 63;               // Wo_foldT[n][k] = sum_h Wo[h*64+k][n]
    float s = 0.f;
    #pragma unroll
    for (int h = 0; h < 8; ++h) s += Wo[(h*64 + k)*512 + n];
    wsu[WS_WOFT + r] = f2bf(s);
    return;
  }

  __shared__ unsigned short Xs[2][2048];      // 2 x (32 rows x 64 k) bf16, XOR-swizzled
  const float* X    = which==0 ? q  : (which==1 ? kmat : v);
  const float* bias = which==0 ? bq : (which==1 ? bk   : bv);
  const float* W    = which==0 ? Wq : (which==1 ? Wk   : Wv);
  const int rowbase = blockIdx.x * 32;
  const int t = threadIdx.x;
  const int w = t >> 6, l = t & 63, g = l >> 4, ln = l & 15;

  f32x4 acc[2][2];                            // [rt][ntl]
  #pragma unroll
  for (int rt = 0; rt < 2; ++rt)
    #pragma unroll
    for (int ntl = 0; ntl < 2; ++ntl) acc[rt][ntl] = (f32x4){0.f,0.f,0.f,0.f};
  float bcol[2];
  #pragma unroll
  for (int ntl = 0; ntl < 2; ++ntl) bcol[ntl] = bias[(w*2+ntl)*16 + ln];

  f32x4 xr[4];
  bf16x8 bc[2][2], bn[2][2];

  #pragma unroll
  for (int j = 0; j < 4; ++j){
    int c = t + j*128; int row = c >> 4, kc = c & 15;
    xr[j] = __builtin_nontemporal_load(reinterpret_cast<const f32x4*>(X + (rowbase+row)*512 + kc*4));
  }
  #pragma unroll
  for (int ntl = 0; ntl < 2; ++ntl)
    #pragma unroll
    for (int kt = 0; kt < 2; ++kt)
      bc[ntl][kt] = wfrag(W, 0*2+kt, w*2+ntl, g, ln);

  #pragma unroll
  for (int i = 0; i < 8; ++i){
    char* Xc = reinterpret_cast<char*>(Xs[i & 1]);
    #pragma unroll
    for (int j = 0; j < 4; ++j){
      int c = t + j*128; int row = c >> 4, kc = c & 15;
      u64 pk = (u64)pk2(xr[j][0], xr[j][1]) | ((u64)pk2(xr[j][2], xr[j][3]) << 32);
      *reinterpret_cast<u64*>(Xc + row*128 + ((kc*8) ^ ((row&7)<<4))) = pk;
    }
    if (i < 7){
      #pragma unroll
      for (int j = 0; j < 4; ++j){
        int c = t + j*128; int row = c >> 4, kc = c & 15;
        xr[j] = __builtin_nontemporal_load(reinterpret_cast<const f32x4*>(X + (rowbase+row)*512 + (i+1)*64 + kc*4));
      }
    }
    __syncthreads();
    if (i < 7){
      #pragma unroll
      for (int ntl = 0; ntl < 2; ++ntl)
        #pragma unroll
        for (int kt = 0; kt < 2; ++kt)
          bn[ntl][kt] = wfrag(W, (i+1)*2+kt, w*2+ntl, g, ln);
    }
    bf16x8 a[2][2];
    #pragma unroll
    for (int rt = 0; rt < 2; ++rt){
      int arow = rt*16 + ln;
      #pragma unroll
      for (int kt = 0; kt < 2; ++kt)
        a[rt][kt] = *reinterpret_cast<const bf16x8*>(Xc + arow*128 + ((kt*64 + g*16) ^ ((arow&7)<<4)));
    }
    #pragma unroll
    for (int ntl = 0; ntl < 2; ++ntl)
      #pragma unroll
      for (int kt = 0; kt < 2; ++kt)
        #pragma unroll
        for (int rt = 0; rt < 2; ++rt)
          acc[rt][ntl] = __builtin_amdgcn_mfma_f32_16x16x32_bf16(a[rt][kt], bc[ntl][kt], acc[rt][ntl], 0, 0, 0);
    if (i < 7){
      #pragma unroll
      for (int ntl = 0; ntl < 2; ++ntl)
        #pragma unroll
        for (int kt = 0; kt < 2; ++kt)
          bc[ntl][kt] = bn[ntl][kt];
    }
  }

  if (which < 2){
    const float sc = (which==0) ? QSCALE : 1.0f;
    unsigned short* outp = wsu + (which==0 ? WS_QP : WS_KP);
    #pragma unroll
    for (int rt = 0; rt < 2; ++rt)
      #pragma unroll
      for (int ntl = 0; ntl < 2; ++ntl)
        #pragma unroll
        for (int r = 0; r < 4; ++r)
          outp[(rowbase + rt*16 + g*4 + r)*64 + (w*2+ntl)*16 + ln] = f2bf((acc[rt][ntl][r] + bcol[ntl]) * sc);
  } else {
    __syncthreads();
    #pragma unroll
    for (int rt = 0; rt < 2; ++rt)
      #pragma unroll
      for (int ntl = 0; ntl < 2; ++ntl)
        #pragma unroll
        for (int r = 0; r < 4; ++r)
          Xs[0][(rt*16 + g*4 + r)*64 + (w*2+ntl)*16 + ln] = f2bf(acc[rt][ntl][r] + bcol[ntl]);
    __syncthreads();
    unsigned short* vpT = wsu + WS_VPT;
    const int b = rowbase >> 11;
    const int kvb = rowbase & 2047;
    const int d = t >> 1, seg = t & 1;
    bf16x8 v0, v1;
    #pragma unroll
    for (int i = 0; i < 8; ++i){
      v0[i] = (short)Xs[0][(seg*16 + i)*64 + d];
      v1[i] = (short)Xs[0][(seg*16 + 8 + i)*64 + d];
    }
    unsigned short* dst = vpT + ((unsigned)(b*64 + d))*2048u + kvb + seg*16;
    *reinterpret_cast<bf16x8*>(dst)     = v0;
    *reinterpret_cast<bf16x8*>(dst + 8) = v1;
  }
}

// ---------------- K2: split-KV flash attention + fused output projection ----
#define PSTR 72

__global__ __launch_bounds__(512) void k_attn(const unsigned short* __restrict__ wsu,
    const float* __restrict__ bo, float* __restrict__ out){
  __shared__ __attribute__((aligned(16))) unsigned char smem[42496];

  const unsigned short* qp   = wsu + WS_QP;
  const unsigned short* kp   = wsu + WS_KP;
  const unsigned short* vpT  = wsu + WS_VPT;
  const unsigned short* WofT = wsu + WS_WOFT;

  const int t = threadIdx.x;
  const int w = t >> 6, l = t & 63, g = l >> 4, ln = l & 15;
  const int batch = blockIdx.y;
  const int qbase = batch*2048 + blockIdx.x*32;

  unsigned short* Pw  = (unsigned short*)(smem + w*4608);
  float*          pls = (float*)(smem + 36864);
  unsigned short* ob  = (unsigned short*)(smem + 37888);

  bf16x8 qa[2][2];
  #pragma unroll
  for (int rt = 0; rt < 2; ++rt)
    #pragma unroll
    for (int kt = 0; kt < 2; ++kt)
      qa[rt][kt] = *reinterpret_cast<const bf16x8*>(qp + (qbase + rt*16 + ln)*64 + kt*32 + g*8);

  f32x4 o[4][2];
  #pragma unroll
  for (int dt = 0; dt < 4; ++dt)
    #pragma unroll
    for (int rt = 0; rt < 2; ++rt) o[dt][rt] = (f32x4){0.f,0.f,0.f,0.f};
  float ls[2] = {0.f, 0.f};

  const unsigned short* kpb = kp  + batch*2048*64;
  const unsigned short* vpb = vpT + batch*64*2048;
  const int kv0 = w * 256;

  #pragma unroll
  for (int it = 0; it < 4; ++it){
    const int kvb = kv0 + it*64;
    bf16x8 ka[4][2];
    #pragma unroll
    for (int ct = 0; ct < 4; ++ct)
      #pragma unroll
      for (int kt = 0; kt < 2; ++kt)
        ka[ct][kt] = *reinterpret_cast<const bf16x8*>(kpb + (kvb + ct*16 + ln)*64 + kt*32 + g*8);
    f32x4 st[4][2];
    #pragma unroll
    for (int ct = 0; ct < 4; ++ct)
      #pragma unroll
      for (int rt = 0; rt < 2; ++rt){
        st[ct][rt] = (f32x4){0.f,0.f,0.f,0.f};
        #pragma unroll
        for (int kt = 0; kt < 2; ++kt)
          st[ct][rt] = __builtin_amdgcn_mfma_f32_16x16x32_bf16(ka[ct][kt], qa[rt][kt], st[ct][rt], 0,0,0);
      }
    bf16x8 vb[4][2];
    #pragma unroll
    for (int dt = 0; dt < 4; ++dt)
      #pragma unroll
      for (int kvt = 0; kvt < 2; ++kvt)
        vb[dt][kvt] = *reinterpret_cast<const bf16x8*>(vpb + (dt*16 + ln)*2048 + kvb + kvt*32 + g*8);

    #pragma unroll
    for (int rt = 0; rt < 2; ++rt){
      float p[4][4];
      float rs = 0.f;
      #pragma unroll
      for (int ct = 0; ct < 4; ++ct)
        #pragma unroll
        for (int r = 0; r < 4; ++r){
          p[ct][r] = exp2f(st[ct][rt][r]);
          rs += p[ct][r];
        }
      rs += __shfl_xor(rs, 16, 64);
      rs += __shfl_xor(rs, 32, 64);
      ls[rt] += rs;
      unsigned short* pr = Pw + (rt*16 + ln)*PSTR;
      #pragma unroll
      for (int ct = 0; ct < 4; ++ct){
        *reinterpret_cast<u32*>(pr + ct*16 + g*4)     = pk2(p[ct][0], p[ct][1]);
        *reinterpret_cast<u32*>(pr + ct*16 + g*4 + 2) = pk2(p[ct][2], p[ct][3]);
      }
    }
    bf16x8 pb[2][2];
    #pragma unroll
    for (int rt = 0; rt < 2; ++rt)
      #pragma unroll
      for (int kvt = 0; kvt < 2; ++kvt)
        pb[rt][kvt] = *reinterpret_cast<const bf16x8*>(Pw + (rt*16 + ln)*PSTR + kvt*32 + g*8);
    #pragma unroll
    for (int dt = 0; dt < 4; ++dt)
      #pragma unroll
      for (int rt = 0; rt < 2; ++rt)
        #pragma unroll
        for (int kvt = 0; kvt < 2; ++kvt)
          o[dt][rt] = __builtin_amdgcn_mfma_f32_16x16x32_bf16(vb[dt][kvt], pb[rt][kvt], o[dt][rt], 0,0,0);
  }

  if (l < 16){ pls[w*32 + ln] = ls[0]; pls[w*32 + 16 + ln] = ls[1]; }
  unsigned short* pow_ = (unsigned short*)(smem + w*4608);
  #pragma unroll
  for (int dt = 0; dt < 4; ++dt)
    #pragma unroll
    for (int rt = 0; rt < 2; ++rt){
      u32* dst = reinterpret_cast<u32*>(pow_ + (rt*16 + ln)*68 + dt*16 + g*4);
      dst[0] = pk2(o[dt][rt][0], o[dt][rt][1]);
      dst[1] = pk2(o[dt][rt][2], o[dt][rt][3]);
    }
  __syncthreads();

  #pragma unroll
  for (int i = 0; i < 4; ++i){
    int idx = t + i*512;
    int row = idx >> 6, d = idx & 63;
    float den = 0.f, num = 0.f;
    #pragma unroll
    for (int w2 = 0; w2 < 8; ++w2){
      den += pls[w2*32 + row];
      num += bf2f(*((const unsigned short*)(smem + w2*4608) + row*68 + d));
    }
    ob[row*PSTR + d] = f2bf(num / den);
  }
  __syncthreads();

  const int colbase = w*64;
  bf16x8 ao[2][2];
  #pragma unroll
  for (int rt = 0; rt < 2; ++rt)
    #pragma unroll
    for (int kt = 0; kt < 2; ++kt)
      ao[rt][kt] = *reinterpret_cast<const bf16x8*>(ob + (rt*16 + ln)*PSTR + kt*32 + g*8);
  f32x4 oc[2][4];
  #pragma unroll
  for (int rt = 0; rt < 2; ++rt)
    #pragma unroll
    for (int nt = 0; nt < 4; ++nt) oc[rt][nt] = (f32x4){0.f,0.f,0.f,0.f};
  #pragma unroll
  for (int nt = 0; nt < 4; ++nt){
    #pragma unroll
    for (int kt = 0; kt < 2; ++kt){
      bf16x8 b = *reinterpret_cast<const bf16x8*>(WofT + (colbase + nt*16 + ln)*64 + kt*32 + g*8);
      #pragma unroll
      for (int rt = 0; rt < 2; ++rt)
        oc[rt][nt] = __builtin_amdgcn_mfma_f32_16x16x32_bf16(ao[rt][kt], b, oc[rt][nt], 0,0,0);
    }
  }
  #pragma unroll
  for (int nt = 0; nt < 4; ++nt){
    float bc = bo[colbase + nt*16 + ln];
    #pragma unroll
    for (int rt = 0; rt < 2; ++rt){
      #pragma unroll
      for (int r = 0; r < 4; ++r){
        int row = qbase + rt*16 + g*4 + r;
        __builtin_nontemporal_store(oc[rt][nt][r] + bc, &out[row*512 + colbase + nt*16 + ln]);
      }
    }
  }
}

extern "C" void kernel_launch(void* const* d_in, const int* in_sizes, int n_in,
                              void* d_out, int out_size, void* d_ws, size_t ws_size,
                              hipStream_t stream){
  const float* q  = (const float*)d_in[0];
  const float* k  = (const float*)d_in[1];
  const float* v  = (const float*)d_in[2];
  const float* Wq = (const float*)d_in[3];
  const float* bq = (const float*)d_in[4];
  const float* Wk = (const float*)d_in[5];
  const float* bk = (const float*)d_in[6];
  const float* Wv = (const float*)d_in[7];
  const float* bv = (const float*)d_in[8];
  const float* Wo = (const float*)d_in[9];
  const float* bo = (const float*)d_in[10];
  float* out = (float*)d_out;
  unsigned short* wsu = (unsigned short*)d_ws;

  k_proj<<<dim3(256, 4), dim3(128), 0, stream>>>(q, k, v, bq, bk, bv, Wq, Wk, Wv, Wo, wsu);
  // MEASUREMENT: k_attn launched 3x (idempotent). dur = env + p + 3a;
  // vs R8 (env + p + a = 43.95) => a = (dur - 43.95)/2, assumption-free.
  k_attn<<<dim3(64, 4), dim3(512), 0, stream>>>(wsu, bo, out);
  k_attn<<<dim3(64, 4), dim3(512), 0, stream>>>(wsu, bo, out);
  k_attn<<<dim3(64, 4), dim3(512), 0, stream>>>(wsu, bo, out);
}

// Round 10
// 49.304 us; speedup vs baseline: 1.7941x; 1.7941x over previous
//
#include <hip/hip_runtime.h>

typedef float f32x4 __attribute__((ext_vector_type(4)));
typedef short bf16x8 __attribute__((ext_vector_type(8)));
typedef __bf16 bf16x2_t __attribute__((ext_vector_type(2)));
typedef unsigned int u32;
typedef unsigned long long u64;

__device__ __forceinline__ u32 pk2(float a, float b){
  bf16x2_t h; h[0] = (__bf16)a; h[1] = (__bf16)b;
  return __builtin_bit_cast(u32, h);
}
__device__ __forceinline__ unsigned short f2bf(float f){
  __bf16 h = (__bf16)f;
  return __builtin_bit_cast(unsigned short, h);
}
__device__ __forceinline__ float bf2f(unsigned short h){
  u32 u = ((u32)h) << 16;
  return __builtin_bit_cast(float, u);
}

// ws layout in ushort (bf16) units
#define WS_WOFT  98304u    // [512][64]  Wo_foldT[n][k] row-major
#define WS_QP    131072u   // [8192][64]  qp * 0.125*log2(e) folded
#define WS_KP    655360u   // [8192][64]
#define WS_VPT   1179648u  // [4][64][2048]  vp transposed per batch

#define QSCALE 0.18033688011112042f   // 0.125 * log2(e)

// B-fragment gather straight from fp32 W (row-major [512][64], L2-resident):
// fragment (kc, cg): lane l, elem j  ->  W[(kc*32 + (l>>4)*8 + j)*64 + cg*16 + (l&15)]
__device__ __forceinline__ bf16x8 wfrag(const float* __restrict__ W, int kc, int cg,
                                        int g, int ln){
  const float* p = W + (size_t)(kc*32 + g*8)*64 + cg*16 + ln;
  union { bf16x8 v8; u32 w[4]; } u;
  #pragma unroll
  for (int j = 0; j < 4; ++j)
    u.w[j] = pk2(p[(2*j)*64], p[(2*j+1)*64]);
  return u.v8;
}

// ---------------- K1: projection GEMMs + Wo fold (grid 256 x 4) -------------
// planes 0/1/2: X @ W, 32 rows/block, 256 threads (4 waves, wave=col-tile),
// 2-deep register prefetch over double-buffered LDS. plane 3: Wo fold.
__global__ __launch_bounds__(256) void k_proj(const float* __restrict__ q,
    const float* __restrict__ kmat, const float* __restrict__ v,
    const float* __restrict__ bq, const float* __restrict__ bk,
    const float* __restrict__ bv, const float* __restrict__ Wq,
    const float* __restrict__ Wk, const float* __restrict__ Wv,
    const float* __restrict__ Wo, unsigned short* __restrict__ wsu){
  const int which = blockIdx.y;
  const int t = threadIdx.x;
  if (which == 3){
    int id = blockIdx.x*256 + t;
    if (id < 32768){
      int n = id >> 6, k = id & 63;           // Wo_foldT[n][k] = sum_h Wo[h*64+k][n]
      float s = 0.f;
      #pragma unroll
      for (int h = 0; h < 8; ++h) s += Wo[(h*64 + k)*512 + n];
      wsu[WS_WOFT + id] = f2bf(s);
    }
    return;
  }

  __shared__ unsigned short Xs[2][2048];      // 2 x (32 rows x 64 k) bf16, XOR-swizzled
  const float* X    = which==0 ? q  : (which==1 ? kmat : v);
  const float* bias = which==0 ? bq : (which==1 ? bk   : bv);
  const float* W    = which==0 ? Wq : (which==1 ? Wk   : Wv);
  const int rowbase = blockIdx.x * 32;
  const int w = t >> 6, l = t & 63, g = l >> 4, ln = l & 15;   // wave w = col tile

  f32x4 acc[2];                               // [rt], cols w*16..+15
  acc[0] = (f32x4){0.f,0.f,0.f,0.f};
  acc[1] = (f32x4){0.f,0.f,0.f,0.f};
  const float bcol = bias[w*16 + ln];

  f32x4 xr[2][2];                             // [parity][j]
  bf16x8 bc[2], bn[2];

  #pragma unroll
  for (int j = 0; j < 2; ++j){
    int c = t + j*256; int row = c >> 4, kc = c & 15;
    xr[0][j] = __builtin_nontemporal_load(reinterpret_cast<const f32x4*>(X + (rowbase+row)*512 + 0*64 + kc*4));
    xr[1][j] = __builtin_nontemporal_load(reinterpret_cast<const f32x4*>(X + (rowbase+row)*512 + 1*64 + kc*4));
  }
  #pragma unroll
  for (int kt = 0; kt < 2; ++kt)
    bc[kt] = wfrag(W, 0*2+kt, w, g, ln);

  #pragma unroll
  for (int i = 0; i < 8; ++i){
    const int par = i & 1;
    char* Xc = reinterpret_cast<char*>(Xs[par]);
    #pragma unroll
    for (int j = 0; j < 2; ++j){
      int c = t + j*256; int row = c >> 4, kc = c & 15;
      u64 pk = (u64)pk2(xr[par][j][0], xr[par][j][1]) | ((u64)pk2(xr[par][j][2], xr[par][j][3]) << 32);
      *reinterpret_cast<u64*>(Xc + row*128 + ((kc*8) ^ ((row&7)<<4))) = pk;
    }
    if (i < 6){
      #pragma unroll
      for (int j = 0; j < 2; ++j){
        int c = t + j*256; int row = c >> 4, kc = c & 15;
        xr[par][j] = __builtin_nontemporal_load(reinterpret_cast<const f32x4*>(X + (rowbase+row)*512 + (i+2)*64 + kc*4));
      }
    }
    __syncthreads();
    if (i < 7){
      #pragma unroll
      for (int kt = 0; kt < 2; ++kt)
        bn[kt] = wfrag(W, (i+1)*2+kt, w, g, ln);
    }
    bf16x8 a[2][2];
    #pragma unroll
    for (int rt = 0; rt < 2; ++rt){
      int arow = rt*16 + ln;
      #pragma unroll
      for (int kt = 0; kt < 2; ++kt)
        a[rt][kt] = *reinterpret_cast<const bf16x8*>(Xc + arow*128 + ((kt*64 + g*16) ^ ((arow&7)<<4)));
    }
    #pragma unroll
    for (int kt = 0; kt < 2; ++kt)
      #pragma unroll
      for (int rt = 0; rt < 2; ++rt)
        acc[rt] = __builtin_amdgcn_mfma_f32_16x16x32_bf16(a[rt][kt], bc[kt], acc[rt], 0, 0, 0);
    if (i < 7){
      bc[0] = bn[0]; bc[1] = bn[1];
    }
  }

  if (which < 2){
    const float sc = (which==0) ? QSCALE : 1.0f;
    unsigned short* outp = wsu + (which==0 ? WS_QP : WS_KP);
    #pragma unroll
    for (int rt = 0; rt < 2; ++rt)
      #pragma unroll
      for (int r = 0; r < 4; ++r)
        outp[(rowbase + rt*16 + g*4 + r)*64 + w*16 + ln] = f2bf((acc[rt][r] + bcol) * sc);
  } else {
    // V: round-trip through LDS, store transposed vpT[b][d][kv]
    __syncthreads();
    #pragma unroll
    for (int rt = 0; rt < 2; ++rt)
      #pragma unroll
      for (int r = 0; r < 4; ++r)
        Xs[0][(rt*16 + g*4 + r)*64 + w*16 + ln] = f2bf(acc[rt][r] + bcol);
    __syncthreads();
    unsigned short* vpT = wsu + WS_VPT;
    const int b = rowbase >> 11;
    const int kvb = rowbase & 2047;
    const int d = t >> 2, seg = t & 3;        // 64 d x 4 segs of 8 kv
    bf16x8 v0;
    #pragma unroll
    for (int i = 0; i < 8; ++i)
      v0[i] = (short)Xs[0][(seg*8 + i)*64 + d];
    *reinterpret_cast<bf16x8*>(vpT + ((unsigned)(b*64 + d))*2048u + kvb + seg*8) = v0;
  }
}

// ---------------- K2: split-KV flash attention + fused output projection ----
// 16 waves/block (1024 thr), kv slice 128/wave, 2 iters of KVBLK=64.
#define PSTR 72
#define NW 16

__global__ __launch_bounds__(1024) void k_attn(const unsigned short* __restrict__ wsu,
    const float* __restrict__ bo, float* __restrict__ out){
  __shared__ __attribute__((aligned(16))) unsigned char smem[80384];
  // [0, 73728)      : per-wave region w*4608: P rows 32 x 144B; reused as po rows 32 x 136B
  // [73728, 75776)  : pls float[16][32]
  // [75776, 80384)  : ob ushort rows 32 x stride 144B

  const unsigned short* qp   = wsu + WS_QP;
  const unsigned short* kp   = wsu + WS_KP;
  const unsigned short* vpT  = wsu + WS_VPT;
  const unsigned short* WofT = wsu + WS_WOFT;

  const int t = threadIdx.x;
  const int w = t >> 6, l = t & 63, g = l >> 4, ln = l & 15;
  const int batch = blockIdx.y;
  const int qbase = batch*2048 + blockIdx.x*32;

  unsigned short* Pw  = (unsigned short*)(smem + w*4608);
  float*          pls = (float*)(smem + 73728);
  unsigned short* ob  = (unsigned short*)(smem + 75776);

  bf16x8 qa[2][2];
  #pragma unroll
  for (int rt = 0; rt < 2; ++rt)
    #pragma unroll
    for (int kt = 0; kt < 2; ++kt)
      qa[rt][kt] = *reinterpret_cast<const bf16x8*>(qp + (qbase + rt*16 + ln)*64 + kt*32 + g*8);

  f32x4 o[4][2];
  #pragma unroll
  for (int dt = 0; dt < 4; ++dt)
    #pragma unroll
    for (int rt = 0; rt < 2; ++rt) o[dt][rt] = (f32x4){0.f,0.f,0.f,0.f};
  float ls[2] = {0.f, 0.f};

  const unsigned short* kpb = kp  + batch*2048*64;
  const unsigned short* vpb = vpT + batch*64*2048;
  const int kv0 = w * 128;                    // this wave's 128-kv slice

  #pragma unroll
  for (int it = 0; it < 2; ++it){
    const int kvb = kv0 + it*64;
    bf16x8 ka[4][2];
    #pragma unroll
    for (int ct = 0; ct < 4; ++ct)
      #pragma unroll
      for (int kt = 0; kt < 2; ++kt)
        ka[ct][kt] = *reinterpret_cast<const bf16x8*>(kpb + (kvb + ct*16 + ln)*64 + kt*32 + g*8);
    f32x4 st[4][2];
    #pragma unroll
    for (int ct = 0; ct < 4; ++ct)
      #pragma unroll
      for (int rt = 0; rt < 2; ++rt){
        st[ct][rt] = (f32x4){0.f,0.f,0.f,0.f};
        #pragma unroll
        for (int kt = 0; kt < 2; ++kt)
          st[ct][rt] = __builtin_amdgcn_mfma_f32_16x16x32_bf16(ka[ct][kt], qa[rt][kt], st[ct][rt], 0,0,0);
      }
    bf16x8 vb[4][2];
    #pragma unroll
    for (int dt = 0; dt < 4; ++dt)
      #pragma unroll
      for (int kvt = 0; kvt < 2; ++kvt)
        vb[dt][kvt] = *reinterpret_cast<const bf16x8*>(vpb + (dt*16 + ln)*2048 + kvb + kvt*32 + g*8);

    #pragma unroll
    for (int rt = 0; rt < 2; ++rt){
      float p[4][4];
      float rs = 0.f;
      #pragma unroll
      for (int ct = 0; ct < 4; ++ct)
        #pragma unroll
        for (int r = 0; r < 4; ++r){
          p[ct][r] = exp2f(st[ct][rt][r]);
          rs += p[ct][r];
        }
      rs += __shfl_xor(rs, 16, 64);
      rs += __shfl_xor(rs, 32, 64);
      ls[rt] += rs;
      unsigned short* pr = Pw + (rt*16 + ln)*PSTR;
      #pragma unroll
      for (int ct = 0; ct < 4; ++ct){
        *reinterpret_cast<u32*>(pr + ct*16 + g*4)     = pk2(p[ct][0], p[ct][1]);
        *reinterpret_cast<u32*>(pr + ct*16 + g*4 + 2) = pk2(p[ct][2], p[ct][3]);
      }
    }
    bf16x8 pb[2][2];
    #pragma unroll
    for (int rt = 0; rt < 2; ++rt)
      #pragma unroll
      for (int kvt = 0; kvt < 2; ++kvt)
        pb[rt][kvt] = *reinterpret_cast<const bf16x8*>(Pw + (rt*16 + ln)*PSTR + kvt*32 + g*8);
    #pragma unroll
    for (int dt = 0; dt < 4; ++dt)
      #pragma unroll
      for (int rt = 0; rt < 2; ++rt)
        #pragma unroll
        for (int kvt = 0; kvt < 2; ++kvt)
          o[dt][rt] = __builtin_amdgcn_mfma_f32_16x16x32_bf16(vb[dt][kvt], pb[rt][kvt], o[dt][rt], 0,0,0);
  }

  if (l < 16){ pls[w*32 + ln] = ls[0]; pls[w*32 + 16 + ln] = ls[1]; }
  unsigned short* pow_ = (unsigned short*)(smem + w*4608);
  #pragma unroll
  for (int dt = 0; dt < 4; ++dt)
    #pragma unroll
    for (int rt = 0; rt < 2; ++rt){
      u32* dst = reinterpret_cast<u32*>(pow_ + (rt*16 + ln)*68 + dt*16 + g*4);
      dst[0] = pk2(o[dt][rt][0], o[dt][rt][1]);
      dst[1] = pk2(o[dt][rt][2], o[dt][rt][3]);
    }
  __syncthreads();

  // merge 16 wave-partials -> normalized O (bf16, stride 72)
  #pragma unroll
  for (int i = 0; i < 2; ++i){
    int idx = t + i*1024;
    int row = idx >> 6, d = idx & 63;
    float den = 0.f, num = 0.f;
    #pragma unroll
    for (int w2 = 0; w2 < NW; ++w2){
      den += pls[w2*32 + row];
      num += bf2f(*((const unsigned short*)(smem + w2*4608) + row*68 + d));
    }
    ob[row*PSTR + d] = f2bf(num / den);
  }
  __syncthreads();

  // output projection: 16 waves: cw = w>>1 col-group (64 cols), rt = w&1 rows
  const int cw = w >> 1, rt = w & 1;
  const int colbase = cw*64;
  bf16x8 ao[2];
  #pragma unroll
  for (int kt = 0; kt < 2; ++kt)
    ao[kt] = *reinterpret_cast<const bf16x8*>(ob + (rt*16 + ln)*PSTR + kt*32 + g*8);
  f32x4 oc[4];
  #pragma unroll
  for (int nt = 0; nt < 4; ++nt) oc[nt] = (f32x4){0.f,0.f,0.f,0.f};
  #pragma unroll
  for (int nt = 0; nt < 4; ++nt){
    #pragma unroll
    for (int kt = 0; kt < 2; ++kt){
      bf16x8 b = *reinterpret_cast<const bf16x8*>(WofT + (colbase + nt*16 + ln)*64 + kt*32 + g*8);
      oc[nt] = __builtin_amdgcn_mfma_f32_16x16x32_bf16(ao[kt], b, oc[nt], 0,0,0);
    }
  }
  #pragma unroll
  for (int nt = 0; nt < 4; ++nt){
    float bc = bo[colbase + nt*16 + ln];
    #pragma unroll
    for (int r = 0; r < 4; ++r){
      int row = qbase + rt*16 + g*4 + r;
      __builtin_nontemporal_store(oc[nt][r] + bc, &out[row*512 + colbase + nt*16 + ln]);
    }
  }
}

extern "C" void kernel_launch(void* const* d_in, const int* in_sizes, int n_in,
                              void* d_out, int out_size, void* d_ws, size_t ws_size,
                              hipStream_t stream){
  const float* q  = (const float*)d_in[0];
  const float* k  = (const float*)d_in[1];
  const float* v  = (const float*)d_in[2];
  const float* Wq = (const float*)d_in[3];
  const float* bq = (const float*)d_in[4];
  const float* Wk = (const float*)d_in[5];
  const float* bk = (const float*)d_in[6];
  const float* Wv = (const float*)d_in[7];
  const float* bv = (const float*)d_in[8];
  const float* Wo = (const float*)d_in[9];
  const float* bo = (const float*)d_in[10];
  float* out = (float*)d_out;
  unsigned short* wsu = (unsigned short*)d_ws;

  k_proj<<<dim3(256, 4), dim3(256), 0, stream>>>(q, k, v, bq, bk, bv, Wq, Wk, Wv, Wo, wsu);
  k_attn<<<dim3(64, 4), dim3(1024), 0, stream>>>(wsu, bo, out);
}

// Round 11
// 34.067 us; speedup vs baseline: 2.5965x; 1.4473x over previous
//
#include <hip/hip_runtime.h>

typedef float f32x4 __attribute__((ext_vector_type(4)));
typedef short bf16x8 __attribute__((ext_vector_type(8)));
typedef __bf16 bf16x2_t __attribute__((ext_vector_type(2)));
typedef unsigned int u32;
typedef unsigned long long u64;

__device__ __forceinline__ u32 pk2(float a, float b){
  bf16x2_t h; h[0] = (__bf16)a; h[1] = (__bf16)b;
  return __builtin_bit_cast(u32, h);
}
__device__ __forceinline__ unsigned short f2bf(float f){
  __bf16 h = (__bf16)f;
  return __builtin_bit_cast(unsigned short, h);
}
__device__ __forceinline__ float bf2f(unsigned short h){
  u32 u = ((u32)h) << 16;
  return __builtin_bit_cast(float, u);
}

// ws layout in ushort units — ALL tensors fragment-packed: frag[idx][lane][8],
// so a wave's MFMA-operand load is base + l*8 (1KB contiguous, coalesced).
// A-fragment semantics (16x16x32): lane l, elem j -> row 16*i16+(l&15), k = kt*32+(l>>4)*8+j
#define WS_WOF   98304u    // Wo_foldT frags: ((c16*2+kt)*64+l)*8+j   (c16 0..31)
#define WS_QF    131072u   // q frags:  ((q16*2+kt)*64+l)*8+j         (q16 0..511)
#define WS_KF    655360u   // k frags:  batch*131072 + ((kv16*2+kt)*64+l)*8+j
#define WS_VF    1179648u  // vT frags: batch*131072 + ((kv32*4+dt)*64+l)*8+j
                           //   lane l: d = dt*16+(l&15), kv = kv32*32+(l>>4)*8+j

#define QSCALE 0.18033688011112042f   // 0.125 * log2(e)

// B-fragment gather straight from fp32 W (row-major [512][64], L1/L2-resident)
__device__ __forceinline__ bf16x8 wfrag(const float* __restrict__ W, int kc, int cg,
                                        int g, int ln){
  const float* p = W + (size_t)(kc*32 + g*8)*64 + cg*16 + ln;
  union { bf16x8 v8; u32 w[4]; } u;
  #pragma unroll
  for (int j = 0; j < 4; ++j)
    u.w[j] = pk2(p[(2*j)*64], p[(2*j+1)*64]);
  return u.v8;
}

// ---------------- K1: projection GEMMs + Wo fold (grid 256 x 4, 128 thr) ----
__global__ __launch_bounds__(128) void k_proj(const float* __restrict__ q,
    const float* __restrict__ kmat, const float* __restrict__ v,
    const float* __restrict__ bq, const float* __restrict__ bk,
    const float* __restrict__ bv, const float* __restrict__ Wq,
    const float* __restrict__ Wk, const float* __restrict__ Wv,
    const float* __restrict__ Wo, unsigned short* __restrict__ wsu){
  const int which = blockIdx.y;
  const int t = threadIdx.x;
  if (which == 3){
    // Wo fold, written directly in fragment order (coalesced store)
    int id = blockIdx.x*128 + t;              // exactly 32768
    int j = id & 7, lf = (id >> 3) & 63, kt = (id >> 9) & 1, c16 = id >> 10;
    int n = c16*16 + (lf & 15), k = kt*32 + (lf >> 4)*8 + j;
    float s = 0.f;
    #pragma unroll
    for (int h = 0; h < 8; ++h) s += Wo[(h*64 + k)*512 + n];
    wsu[WS_WOF + id] = f2bf(s);
    return;
  }

  __shared__ unsigned short Xs[2][2048];      // dbuf staging; Xs[0] reused by epilogue
  const float* X    = which==0 ? q  : (which==1 ? kmat : v);
  const float* bias = which==0 ? bq : (which==1 ? bk   : bv);
  const float* W    = which==0 ? Wq : (which==1 ? Wk   : Wv);
  const int rowbase = blockIdx.x * 32;
  const int w = t >> 6, l = t & 63, g = l >> 4, ln = l & 15;

  f32x4 acc[2][2];                            // [rt][ntl]
  #pragma unroll
  for (int rt = 0; rt < 2; ++rt)
    #pragma unroll
    for (int ntl = 0; ntl < 2; ++ntl) acc[rt][ntl] = (f32x4){0.f,0.f,0.f,0.f};
  float bcol[2];
  #pragma unroll
  for (int ntl = 0; ntl < 2; ++ntl) bcol[ntl] = bias[(w*2+ntl)*16 + ln];

  f32x4 xr[4];
  bf16x8 bc[2][2], bn[2][2];

  #pragma unroll
  for (int j = 0; j < 4; ++j){
    int c = t + j*128; int row = c >> 4, kc = c & 15;
    xr[j] = __builtin_nontemporal_load(reinterpret_cast<const f32x4*>(X + (rowbase+row)*512 + kc*4));
  }
  #pragma unroll
  for (int ntl = 0; ntl < 2; ++ntl)
    #pragma unroll
    for (int kt = 0; kt < 2; ++kt)
      bc[ntl][kt] = wfrag(W, 0*2+kt, w*2+ntl, g, ln);

  #pragma unroll
  for (int i = 0; i < 8; ++i){
    char* Xc = reinterpret_cast<char*>(Xs[i & 1]);
    #pragma unroll
    for (int j = 0; j < 4; ++j){
      int c = t + j*128; int row = c >> 4, kc = c & 15;
      u64 pk = (u64)pk2(xr[j][0], xr[j][1]) | ((u64)pk2(xr[j][2], xr[j][3]) << 32);
      *reinterpret_cast<u64*>(Xc + row*128 + ((kc*8) ^ ((row&7)<<4))) = pk;
    }
    if (i < 7){
      #pragma unroll
      for (int j = 0; j < 4; ++j){
        int c = t + j*128; int row = c >> 4, kc = c & 15;
        xr[j] = __builtin_nontemporal_load(reinterpret_cast<const f32x4*>(X + (rowbase+row)*512 + (i+1)*64 + kc*4));
      }
    }
    __syncthreads();
    if (i < 7){
      #pragma unroll
      for (int ntl = 0; ntl < 2; ++ntl)
        #pragma unroll
        for (int kt = 0; kt < 2; ++kt)
          bn[ntl][kt] = wfrag(W, (i+1)*2+kt, w*2+ntl, g, ln);
    }
    bf16x8 a[2][2];
    #pragma unroll
    for (int rt = 0; rt < 2; ++rt){
      int arow = rt*16 + ln;
      #pragma unroll
      for (int kt = 0; kt < 2; ++kt)
        a[rt][kt] = *reinterpret_cast<const bf16x8*>(Xc + arow*128 + ((kt*64 + g*16) ^ ((arow&7)<<4)));
    }
    #pragma unroll
    for (int ntl = 0; ntl < 2; ++ntl)
      #pragma unroll
      for (int kt = 0; kt < 2; ++kt)
        #pragma unroll
        for (int rt = 0; rt < 2; ++rt)
          acc[rt][ntl] = __builtin_amdgcn_mfma_f32_16x16x32_bf16(a[rt][kt], bc[ntl][kt], acc[rt][ntl], 0, 0, 0);
    if (i < 7){
      #pragma unroll
      for (int ntl = 0; ntl < 2; ++ntl)
        #pragma unroll
        for (int kt = 0; kt < 2; ++kt)
          bc[ntl][kt] = bn[ntl][kt];
    }
  }

  char* Xb = reinterpret_cast<char*>(Xs[0]);
  __syncthreads();
  if (which < 2){
    // repack acc -> swizzled 32x64 LDS tile -> fragment order -> coalesced 1KB stores
    const float sc = (which==0) ? QSCALE : 1.0f;
    #pragma unroll
    for (int rt = 0; rt < 2; ++rt)
      #pragma unroll
      for (int ntl = 0; ntl < 2; ++ntl)
        #pragma unroll
        for (int r = 0; r < 4; ++r){
          int row = rt*16 + g*4 + r, col = (w*2+ntl)*16 + ln;
          *reinterpret_cast<unsigned short*>(Xb + row*128 + ((col*2) ^ ((row&7)<<4))) =
              f2bf((acc[rt][ntl][r] + bcol[ntl]) * sc);
        }
    __syncthreads();
    unsigned short* base = (which==0)
        ? wsu + WS_QF + (unsigned)(((rowbase>>4) + w)*2)*512u
        : wsu + WS_KF + (unsigned)(rowbase>>11)*131072u + (unsigned)((((rowbase&2047)>>4) + w)*2)*512u;
    const int arow = w*16 + ln;
    #pragma unroll
    for (int kt = 0; kt < 2; ++kt){
      bf16x8 f = *reinterpret_cast<const bf16x8*>(Xb + arow*128 + ((kt*64 + g*16) ^ ((arow&7)<<4)));
      *reinterpret_cast<bf16x8*>(base + kt*512 + l*8) = f;
    }
  } else {
    // V: transposed 64x32 LDS tile (swizzled) -> V^T fragments -> coalesced stores
    #pragma unroll
    for (int rt = 0; rt < 2; ++rt)
      #pragma unroll
      for (int ntl = 0; ntl < 2; ++ntl)
        #pragma unroll
        for (int r = 0; r < 4; ++r){
          int kv = rt*16 + g*4 + r, d = (w*2+ntl)*16 + ln;
          *reinterpret_cast<unsigned short*>(Xb + d*64 + ((kv*2) ^ ((d&3)<<4))) =
              f2bf(acc[rt][ntl][r] + bcol[ntl]);
        }
    __syncthreads();
    unsigned short* vfb = wsu + WS_VF + (unsigned)(rowbase>>11)*131072u;
    const int kv32 = (rowbase & 2047) >> 5;
    #pragma unroll
    for (int dtl = 0; dtl < 2; ++dtl){
      int dt = w*2 + dtl;
      int rd = dt*16 + ln;
      bf16x8 f = *reinterpret_cast<const bf16x8*>(Xb + rd*64 + ((g*16) ^ ((rd&3)<<4)));
      *reinterpret_cast<bf16x8*>(vfb + (unsigned)((kv32*4 + dt)*64 + l)*8u) = f;
    }
  }
}

// ---------------- K2: split-KV flash attention + fused output projection ----
// R8 structure (512 thr, 8 waves, kv slice 256, 4 iters) — only loads changed
// to fragment-packed (coalesced).
#define PSTR 72

__global__ __launch_bounds__(512) void k_attn(const unsigned short* __restrict__ wsu,
    const float* __restrict__ bo, float* __restrict__ out){
  __shared__ __attribute__((aligned(16))) unsigned char smem[42496];

  const int t = threadIdx.x;
  const int w = t >> 6, l = t & 63, g = l >> 4, ln = l & 15;
  const int batch = blockIdx.y;
  const int qbase = batch*2048 + blockIdx.x*32;

  const unsigned short* qf  = wsu + WS_QF;
  const unsigned short* kfb = wsu + WS_KF + (unsigned)batch*131072u;
  const unsigned short* vfb = wsu + WS_VF + (unsigned)batch*131072u;
  const unsigned short* wof = wsu + WS_WOF;

  unsigned short* Pw  = (unsigned short*)(smem + w*4608);
  float*          pls = (float*)(smem + 36864);
  unsigned short* ob  = (unsigned short*)(smem + 37888);

  const int q16 = qbase >> 4;
  bf16x8 qa[2][2];
  #pragma unroll
  for (int rt = 0; rt < 2; ++rt)
    #pragma unroll
    for (int kt = 0; kt < 2; ++kt)
      qa[rt][kt] = *reinterpret_cast<const bf16x8*>(qf + (unsigned)(((q16+rt)*2 + kt)*64 + l)*8u);

  f32x4 o[4][2];
  #pragma unroll
  for (int dt = 0; dt < 4; ++dt)
    #pragma unroll
    for (int rt = 0; rt < 2; ++rt) o[dt][rt] = (f32x4){0.f,0.f,0.f,0.f};
  float ls[2] = {0.f, 0.f};

  const int kv0 = w * 256;

  #pragma unroll
  for (int it = 0; it < 4; ++it){
    const int kvb = kv0 + it*64;
    const int kv16 = kvb >> 4, kv32 = kvb >> 5;
    bf16x8 ka[4][2];
    #pragma unroll
    for (int ct = 0; ct < 4; ++ct)
      #pragma unroll
      for (int kt = 0; kt < 2; ++kt)
        ka[ct][kt] = *reinterpret_cast<const bf16x8*>(kfb + (unsigned)(((kv16+ct)*2 + kt)*64 + l)*8u);
    f32x4 st[4][2];
    #pragma unroll
    for (int ct = 0; ct < 4; ++ct)
      #pragma unroll
      for (int rt = 0; rt < 2; ++rt){
        st[ct][rt] = (f32x4){0.f,0.f,0.f,0.f};
        #pragma unroll
        for (int kt = 0; kt < 2; ++kt)
          st[ct][rt] = __builtin_amdgcn_mfma_f32_16x16x32_bf16(ka[ct][kt], qa[rt][kt], st[ct][rt], 0,0,0);
      }
    bf16x8 vb[4][2];
    #pragma unroll
    for (int dt = 0; dt < 4; ++dt)
      #pragma unroll
      for (int kvt = 0; kvt < 2; ++kvt)
        vb[dt][kvt] = *reinterpret_cast<const bf16x8*>(vfb + (unsigned)(((kv32+kvt)*4 + dt)*64 + l)*8u);

    #pragma unroll
    for (int rt = 0; rt < 2; ++rt){
      float p[4][4];
      float rs = 0.f;
      #pragma unroll
      for (int ct = 0; ct < 4; ++ct)
        #pragma unroll
        for (int r = 0; r < 4; ++r){
          p[ct][r] = exp2f(st[ct][rt][r]);
          rs += p[ct][r];
        }
      rs += __shfl_xor(rs, 16, 64);
      rs += __shfl_xor(rs, 32, 64);
      ls[rt] += rs;
      unsigned short* pr = Pw + (rt*16 + ln)*PSTR;
      #pragma unroll
      for (int ct = 0; ct < 4; ++ct){
        *reinterpret_cast<u32*>(pr + ct*16 + g*4)     = pk2(p[ct][0], p[ct][1]);
        *reinterpret_cast<u32*>(pr + ct*16 + g*4 + 2) = pk2(p[ct][2], p[ct][3]);
      }
    }
    bf16x8 pb[2][2];
    #pragma unroll
    for (int rt = 0; rt < 2; ++rt)
      #pragma unroll
      for (int kvt = 0; kvt < 2; ++kvt)
        pb[rt][kvt] = *reinterpret_cast<const bf16x8*>(Pw + (rt*16 + ln)*PSTR + kvt*32 + g*8);
    #pragma unroll
    for (int dt = 0; dt < 4; ++dt)
      #pragma unroll
      for (int rt = 0; rt < 2; ++rt)
        #pragma unroll
        for (int kvt = 0; kvt < 2; ++kvt)
          o[dt][rt] = __builtin_amdgcn_mfma_f32_16x16x32_bf16(vb[dt][kvt], pb[rt][kvt], o[dt][rt], 0,0,0);
  }

  if (l < 16){ pls[w*32 + ln] = ls[0]; pls[w*32 + 16 + ln] = ls[1]; }
  unsigned short* pow_ = (unsigned short*)(smem + w*4608);
  #pragma unroll
  for (int dt = 0; dt < 4; ++dt)
    #pragma unroll
    for (int rt = 0; rt < 2; ++rt){
      u32* dst = reinterpret_cast<u32*>(pow_ + (rt*16 + ln)*68 + dt*16 + g*4);
      dst[0] = pk2(o[dt][rt][0], o[dt][rt][1]);
      dst[1] = pk2(o[dt][rt][2], o[dt][rt][3]);
    }
  __syncthreads();

  #pragma unroll
  for (int i = 0; i < 4; ++i){
    int idx = t + i*512;
    int row = idx >> 6, d = idx & 63;
    float den = 0.f, num = 0.f;
    #pragma unroll
    for (int w2 = 0; w2 < 8; ++w2){
      den += pls[w2*32 + row];
      num += bf2f(*((const unsigned short*)(smem + w2*4608) + row*68 + d));
    }
    ob[row*PSTR + d] = f2bf(num / den);
  }
  __syncthreads();

  const int colbase = w*64;
  bf16x8 ao[2][2];
  #pragma unroll
  for (int rt = 0; rt < 2; ++rt)
    #pragma unroll
    for (int kt = 0; kt < 2; ++kt)
      ao[rt][kt] = *reinterpret_cast<const bf16x8*>(ob + (rt*16 + ln)*PSTR + kt*32 + g*8);
  f32x4 oc[2][4];
  #pragma unroll
  for (int rt = 0; rt < 2; ++rt)
    #pragma unroll
    for (int nt = 0; nt < 4; ++nt) oc[rt][nt] = (f32x4){0.f,0.f,0.f,0.f};
  #pragma unroll
  for (int nt = 0; nt < 4; ++nt){
    #pragma unroll
    for (int kt = 0; kt < 2; ++kt){
      bf16x8 b = *reinterpret_cast<const bf16x8*>(wof + (unsigned)(((w*4+nt)*2 + kt)*64 + l)*8u);
      #pragma unroll
      for (int rt = 0; rt < 2; ++rt)
        oc[rt][nt] = __builtin_amdgcn_mfma_f32_16x16x32_bf16(ao[rt][kt], b, oc[rt][nt], 0,0,0);
    }
  }
  #pragma unroll
  for (int nt = 0; nt < 4; ++nt){
    float bc = bo[colbase + nt*16 + ln];
    #pragma unroll
    for (int rt = 0; rt < 2; ++rt){
      #pragma unroll
      for (int r = 0; r < 4; ++r){
        int row = qbase + rt*16 + g*4 + r;
        __builtin_nontemporal_store(oc[rt][nt][r] + bc, &out[row*512 + colbase + nt*16 + ln]);
      }
    }
  }
}

extern "C" void kernel_launch(void* const* d_in, const int* in_sizes, int n_in,
                              void* d_out, int out_size, void* d_ws, size_t ws_size,
                              hipStream_t stream){
  const float* q  = (const float*)d_in[0];
  const float* k  = (const float*)d_in[1];
  const float* v  = (const float*)d_in[2];
  const float* Wq = (const float*)d_in[3];
  const float* bq = (const float*)d_in[4];
  const float* Wk = (const float*)d_in[5];
  const float* bk = (const float*)d_in[6];
  const float* Wv = (const float*)d_in[7];
  const float* bv = (const float*)d_in[8];
  const float* Wo = (const float*)d_in[9];
  const float* bo = (const float*)d_in[10];
  float* out = (float*)d_out;
  unsigned short* wsu = (unsigned short*)d_ws;

  k_proj<<<dim3(256, 4), dim3(128), 0, stream>>>(q, k, v, bq, bk, bv, Wq, Wk, Wv, Wo, wsu);
  k_attn<<<dim3(64, 4), dim3(512), 0, stream>>>(wsu, bo, out);
}

// Round 12
// 32.817 us; speedup vs baseline: 2.6954x; 1.0381x over previous
//
#include <hip/hip_runtime.h>

typedef float f32x4 __attribute__((ext_vector_type(4)));
typedef short bf16x8 __attribute__((ext_vector_type(8)));
typedef __bf16 bf16x2_t __attribute__((ext_vector_type(2)));
typedef unsigned int u32;
typedef unsigned long long u64;

__device__ __forceinline__ u32 pk2(float a, float b){
  bf16x2_t h; h[0] = (__bf16)a; h[1] = (__bf16)b;
  return __builtin_bit_cast(u32, h);
}
__device__ __forceinline__ unsigned short f2bf(float f){
  __bf16 h = (__bf16)f;
  return __builtin_bit_cast(unsigned short, h);
}
__device__ __forceinline__ float bf2f(unsigned short h){
  u32 u = ((u32)h) << 16;
  return __builtin_bit_cast(float, u);
}

// ws layout in ushort units — ALL tensors fragment-packed: frag[idx][lane][8],
// so a wave's MFMA-operand load is base + l*8 (1KB contiguous, coalesced).
#define WS_WOF   98304u    // Wo_foldT frags: ((c16*2+kt)*64+l)*8+j   (c16 0..31)
#define WS_QF    131072u   // q frags:  ((q16*2+kt)*64+l)*8+j         (q16 0..511)
#define WS_KF    655360u   // k frags:  batch*131072 + ((kv16*2+kt)*64+l)*8+j
#define WS_VF    1179648u  // vT frags: batch*131072 + ((kv32*4+dt)*64+l)*8+j

#define QSCALE 0.18033688011112042f   // 0.125 * log2(e)

// B-fragment gather straight from fp32 W (row-major [512][64], L1/L2-resident)
__device__ __forceinline__ bf16x8 wfrag(const float* __restrict__ W, int kc, int cg,
                                        int g, int ln){
  const float* p = W + (size_t)(kc*32 + g*8)*64 + cg*16 + ln;
  union { bf16x8 v8; u32 w[4]; } u;
  #pragma unroll
  for (int j = 0; j < 4; ++j)
    u.w[j] = pk2(p[(2*j)*64], p[(2*j+1)*64]);
  return u.v8;
}

// ---------------- K1: projection GEMMs + Wo fold (grid 256 x 4, 128 thr) ----
__global__ __launch_bounds__(128) void k_proj(const float* __restrict__ q,
    const float* __restrict__ kmat, const float* __restrict__ v,
    const float* __restrict__ bq, const float* __restrict__ bk,
    const float* __restrict__ bv, const float* __restrict__ Wq,
    const float* __restrict__ Wk, const float* __restrict__ Wv,
    const float* __restrict__ Wo, unsigned short* __restrict__ wsu){
  const int which = blockIdx.y;
  const int t = threadIdx.x;
  if (which == 3){
    // Wo fold, written directly in fragment order (coalesced store)
    int id = blockIdx.x*128 + t;              // exactly 32768
    int j = id & 7, lf = (id >> 3) & 63, kt = (id >> 9) & 1, c16 = id >> 10;
    int n = c16*16 + (lf & 15), k = kt*32 + (lf >> 4)*8 + j;
    float s = 0.f;
    #pragma unroll
    for (int h = 0; h < 8; ++h) s += Wo[(h*64 + k)*512 + n];
    wsu[WS_WOF + id] = f2bf(s);
    return;
  }

  __shared__ unsigned short Xs[2][2048];      // dbuf staging; Xs[0] reused by epilogue
  const float* X    = which==0 ? q  : (which==1 ? kmat : v);
  const float* bias = which==0 ? bq : (which==1 ? bk   : bv);
  const float* W    = which==0 ? Wq : (which==1 ? Wk   : Wv);
  const int rowbase = blockIdx.x * 32;
  const int w = t >> 6, l = t & 63, g = l >> 4, ln = l & 15;

  f32x4 acc[2][2];                            // [rt][ntl]
  #pragma unroll
  for (int rt = 0; rt < 2; ++rt)
    #pragma unroll
    for (int ntl = 0; ntl < 2; ++ntl) acc[rt][ntl] = (f32x4){0.f,0.f,0.f,0.f};
  float bcol[2];
  #pragma unroll
  for (int ntl = 0; ntl < 2; ++ntl) bcol[ntl] = bias[(w*2+ntl)*16 + ln];

  f32x4 xr[4];
  bf16x8 bc[2][2], bn[2][2];

  #pragma unroll
  for (int j = 0; j < 4; ++j){
    int c = t + j*128; int row = c >> 4, kc = c & 15;
    xr[j] = __builtin_nontemporal_load(reinterpret_cast<const f32x4*>(X + (rowbase+row)*512 + kc*4));
  }
  #pragma unroll
  for (int ntl = 0; ntl < 2; ++ntl)
    #pragma unroll
    for (int kt = 0; kt < 2; ++kt)
      bc[ntl][kt] = wfrag(W, 0*2+kt, w*2+ntl, g, ln);

  #pragma unroll
  for (int i = 0; i < 8; ++i){
    char* Xc = reinterpret_cast<char*>(Xs[i & 1]);
    #pragma unroll
    for (int j = 0; j < 4; ++j){
      int c = t + j*128; int row = c >> 4, kc = c & 15;
      u64 pk = (u64)pk2(xr[j][0], xr[j][1]) | ((u64)pk2(xr[j][2], xr[j][3]) << 32);
      *reinterpret_cast<u64*>(Xc + row*128 + ((kc*8) ^ ((row&7)<<4))) = pk;
    }
    if (i < 7){
      #pragma unroll
      for (int j = 0; j < 4; ++j){
        int c = t + j*128; int row = c >> 4, kc = c & 15;
        xr[j] = __builtin_nontemporal_load(reinterpret_cast<const f32x4*>(X + (rowbase+row)*512 + (i+1)*64 + kc*4));
      }
    }
    __syncthreads();
    if (i < 7){
      #pragma unroll
      for (int ntl = 0; ntl < 2; ++ntl)
        #pragma unroll
        for (int kt = 0; kt < 2; ++kt)
          bn[ntl][kt] = wfrag(W, (i+1)*2+kt, w*2+ntl, g, ln);
    }
    bf16x8 a[2][2];
    #pragma unroll
    for (int rt = 0; rt < 2; ++rt){
      int arow = rt*16 + ln;
      #pragma unroll
      for (int kt = 0; kt < 2; ++kt)
        a[rt][kt] = *reinterpret_cast<const bf16x8*>(Xc + arow*128 + ((kt*64 + g*16) ^ ((arow&7)<<4)));
    }
    #pragma unroll
    for (int ntl = 0; ntl < 2; ++ntl)
      #pragma unroll
      for (int kt = 0; kt < 2; ++kt)
        #pragma unroll
        for (int rt = 0; rt < 2; ++rt)
          acc[rt][ntl] = __builtin_amdgcn_mfma_f32_16x16x32_bf16(a[rt][kt], bc[ntl][kt], acc[rt][ntl], 0, 0, 0);
    if (i < 7){
      #pragma unroll
      for (int ntl = 0; ntl < 2; ++ntl)
        #pragma unroll
        for (int kt = 0; kt < 2; ++kt)
          bc[ntl][kt] = bn[ntl][kt];
    }
  }

  char* Xb = reinterpret_cast<char*>(Xs[0]);
  __syncthreads();
  if (which < 2){
    // repack acc -> swizzled 32x64 LDS tile -> fragment order -> coalesced 1KB stores
    const float sc = (which==0) ? QSCALE : 1.0f;
    #pragma unroll
    for (int rt = 0; rt < 2; ++rt)
      #pragma unroll
      for (int ntl = 0; ntl < 2; ++ntl)
        #pragma unroll
        for (int r = 0; r < 4; ++r){
          int row = rt*16 + g*4 + r, col = (w*2+ntl)*16 + ln;
          *reinterpret_cast<unsigned short*>(Xb + row*128 + ((col*2) ^ ((row&7)<<4))) =
              f2bf((acc[rt][ntl][r] + bcol[ntl]) * sc);
        }
    __syncthreads();
    unsigned short* base = (which==0)
        ? wsu + WS_QF + (unsigned)(((rowbase>>4) + w)*2)*512u
        : wsu + WS_KF + (unsigned)(rowbase>>11)*131072u + (unsigned)((((rowbase&2047)>>4) + w)*2)*512u;
    const int arow = w*16 + ln;
    #pragma unroll
    for (int kt = 0; kt < 2; ++kt){
      bf16x8 f = *reinterpret_cast<const bf16x8*>(Xb + arow*128 + ((kt*64 + g*16) ^ ((arow&7)<<4)));
      *reinterpret_cast<bf16x8*>(base + kt*512 + l*8) = f;
    }
  } else {
    // V: transposed 64x32 LDS tile (swizzled) -> V^T fragments -> coalesced stores
    #pragma unroll
    for (int rt = 0; rt < 2; ++rt)
      #pragma unroll
      for (int ntl = 0; ntl < 2; ++ntl)
        #pragma unroll
        for (int r = 0; r < 4; ++r){
          int kv = rt*16 + g*4 + r, d = (w*2+ntl)*16 + ln;
          *reinterpret_cast<unsigned short*>(Xb + d*64 + ((kv*2) ^ ((d&3)<<4))) =
              f2bf(acc[rt][ntl][r] + bcol[ntl]);
        }
    __syncthreads();
    unsigned short* vfb = wsu + WS_VF + (unsigned)(rowbase>>11)*131072u;
    const int kv32 = (rowbase & 2047) >> 5;
    #pragma unroll
    for (int dtl = 0; dtl < 2; ++dtl){
      int dt = w*2 + dtl;
      int rd = dt*16 + ln;
      bf16x8 f = *reinterpret_cast<const bf16x8*>(Xb + rd*64 + ((g*16) ^ ((rd&3)<<4)));
      *reinterpret_cast<bf16x8*>(vfb + (unsigned)((kv32*4 + dt)*64 + l)*8u) = f;
    }
  }
}

// ---------------- K2: split-KV flash attention + fused output projection ----
// R11 structure; grid flattened to 1D 256 with XCD-aware mapping: all blocks
// on one XCD share a batch -> K/V frags read from L3 once per XCD, then L2-hit.
#define PSTR 72

__global__ __launch_bounds__(512) void k_attn(const unsigned short* __restrict__ wsu,
    const float* __restrict__ bo, float* __restrict__ out){
  __shared__ __attribute__((aligned(16))) unsigned char smem[42496];

  const int t = threadIdx.x;
  const int w = t >> 6, l = t & 63, g = l >> 4, ln = l & 15;
  // XCD-aware mapping (round-robin wgid->XCD assumed; affects speed only):
  // xcd = bid%8 ; batch = xcd>>1 ; tile = (bid&1)*32 + bid>>3
  const int bid = blockIdx.x;
  const int batch = (bid & 7) >> 1;
  const int tile  = ((bid & 1) << 5) | (bid >> 3);
  const int qbase = batch*2048 + tile*32;

  const unsigned short* qf  = wsu + WS_QF;
  const unsigned short* kfb = wsu + WS_KF + (unsigned)batch*131072u;
  const unsigned short* vfb = wsu + WS_VF + (unsigned)batch*131072u;
  const unsigned short* wof = wsu + WS_WOF;

  unsigned short* Pw  = (unsigned short*)(smem + w*4608);
  float*          pls = (float*)(smem + 36864);
  unsigned short* ob  = (unsigned short*)(smem + 37888);

  const int q16 = qbase >> 4;
  bf16x8 qa[2][2];
  #pragma unroll
  for (int rt = 0; rt < 2; ++rt)
    #pragma unroll
    for (int kt = 0; kt < 2; ++kt)
      qa[rt][kt] = *reinterpret_cast<const bf16x8*>(qf + (unsigned)(((q16+rt)*2 + kt)*64 + l)*8u);

  f32x4 o[4][2];
  #pragma unroll
  for (int dt = 0; dt < 4; ++dt)
    #pragma unroll
    for (int rt = 0; rt < 2; ++rt) o[dt][rt] = (f32x4){0.f,0.f,0.f,0.f};
  float ls[2] = {0.f, 0.f};

  const int kv0 = w * 256;

  #pragma unroll
  for (int it = 0; it < 4; ++it){
    const int kvb = kv0 + it*64;
    const int kv16 = kvb >> 4, kv32 = kvb >> 5;
    bf16x8 ka[4][2];
    #pragma unroll
    for (int ct = 0; ct < 4; ++ct)
      #pragma unroll
      for (int kt = 0; kt < 2; ++kt)
        ka[ct][kt] = *reinterpret_cast<const bf16x8*>(kfb + (unsigned)(((kv16+ct)*2 + kt)*64 + l)*8u);
    f32x4 st[4][2];
    #pragma unroll
    for (int ct = 0; ct < 4; ++ct)
      #pragma unroll
      for (int rt = 0; rt < 2; ++rt){
        st[ct][rt] = (f32x4){0.f,0.f,0.f,0.f};
        #pragma unroll
        for (int kt = 0; kt < 2; ++kt)
          st[ct][rt] = __builtin_amdgcn_mfma_f32_16x16x32_bf16(ka[ct][kt], qa[rt][kt], st[ct][rt], 0,0,0);
      }
    bf16x8 vb[4][2];
    #pragma unroll
    for (int dt = 0; dt < 4; ++dt)
      #pragma unroll
      for (int kvt = 0; kvt < 2; ++kvt)
        vb[dt][kvt] = *reinterpret_cast<const bf16x8*>(vfb + (unsigned)(((kv32+kvt)*4 + dt)*64 + l)*8u);

    #pragma unroll
    for (int rt = 0; rt < 2; ++rt){
      float p[4][4];
      float rs = 0.f;
      #pragma unroll
      for (int ct = 0; ct < 4; ++ct)
        #pragma unroll
        for (int r = 0; r < 4; ++r){
          p[ct][r] = exp2f(st[ct][rt][r]);
          rs += p[ct][r];
        }
      rs += __shfl_xor(rs, 16, 64);
      rs += __shfl_xor(rs, 32, 64);
      ls[rt] += rs;
      unsigned short* pr = Pw + (rt*16 + ln)*PSTR;
      #pragma unroll
      for (int ct = 0; ct < 4; ++ct){
        *reinterpret_cast<u32*>(pr + ct*16 + g*4)     = pk2(p[ct][0], p[ct][1]);
        *reinterpret_cast<u32*>(pr + ct*16 + g*4 + 2) = pk2(p[ct][2], p[ct][3]);
      }
    }
    bf16x8 pb[2][2];
    #pragma unroll
    for (int rt = 0; rt < 2; ++rt)
      #pragma unroll
      for (int kvt = 0; kvt < 2; ++kvt)
        pb[rt][kvt] = *reinterpret_cast<const bf16x8*>(Pw + (rt*16 + ln)*PSTR + kvt*32 + g*8);
    #pragma unroll
    for (int dt = 0; dt < 4; ++dt)
      #pragma unroll
      for (int rt = 0; rt < 2; ++rt)
        #pragma unroll
        for (int kvt = 0; kvt < 2; ++kvt)
          o[dt][rt] = __builtin_amdgcn_mfma_f32_16x16x32_bf16(vb[dt][kvt], pb[rt][kvt], o[dt][rt], 0,0,0);
  }

  if (l < 16){ pls[w*32 + ln] = ls[0]; pls[w*32 + 16 + ln] = ls[1]; }
  unsigned short* pow_ = (unsigned short*)(smem + w*4608);
  #pragma unroll
  for (int dt = 0; dt < 4; ++dt)
    #pragma unroll
    for (int rt = 0; rt < 2; ++rt){
      u32* dst = reinterpret_cast<u32*>(pow_ + (rt*16 + ln)*68 + dt*16 + g*4);
      dst[0] = pk2(o[dt][rt][0], o[dt][rt][1]);
      dst[1] = pk2(o[dt][rt][2], o[dt][rt][3]);
    }
  __syncthreads();

  #pragma unroll
  for (int i = 0; i < 4; ++i){
    int idx = t + i*512;
    int row = idx >> 6, d = idx & 63;
    float den = 0.f, num = 0.f;
    #pragma unroll
    for (int w2 = 0; w2 < 8; ++w2){
      den += pls[w2*32 + row];
      num += bf2f(*((const unsigned short*)(smem + w2*4608) + row*68 + d));
    }
    ob[row*PSTR + d] = f2bf(num / den);
  }
  __syncthreads();

  const int colbase = w*64;
  bf16x8 ao[2][2];
  #pragma unroll
  for (int rt = 0; rt < 2; ++rt)
    #pragma unroll
    for (int kt = 0; kt < 2; ++kt)
      ao[rt][kt] = *reinterpret_cast<const bf16x8*>(ob + (rt*16 + ln)*PSTR + kt*32 + g*8);
  f32x4 oc[2][4];
  #pragma unroll
  for (int rt = 0; rt < 2; ++rt)
    #pragma unroll
    for (int nt = 0; nt < 4; ++nt) oc[rt][nt] = (f32x4){0.f,0.f,0.f,0.f};
  #pragma unroll
  for (int nt = 0; nt < 4; ++nt){
    #pragma unroll
    for (int kt = 0; kt < 2; ++kt){
      bf16x8 b = *reinterpret_cast<const bf16x8*>(wof + (unsigned)(((w*4+nt)*2 + kt)*64 + l)*8u);
      #pragma unroll
      for (int rt = 0; rt < 2; ++rt)
        oc[rt][nt] = __builtin_amdgcn_mfma_f32_16x16x32_bf16(ao[rt][kt], b, oc[rt][nt], 0,0,0);
    }
  }
  #pragma unroll
  for (int nt = 0; nt < 4; ++nt){
    float bc = bo[colbase + nt*16 + ln];
    #pragma unroll
    for (int rt = 0; rt < 2; ++rt){
      #pragma unroll
      for (int r = 0; r < 4; ++r){
        int row = qbase + rt*16 + g*4 + r;
        __builtin_nontemporal_store(oc[rt][nt][r] + bc, &out[row*512 + colbase + nt*16 + ln]);
      }
    }
  }
}

extern "C" void kernel_launch(void* const* d_in, const int* in_sizes, int n_in,
                              void* d_out, int out_size, void* d_ws, size_t ws_size,
                              hipStream_t stream){
  const float* q  = (const float*)d_in[0];
  const float* k  = (const float*)d_in[1];
  const float* v  = (const float*)d_in[2];
  const float* Wq = (const float*)d_in[3];
  const float* bq = (const float*)d_in[4];
  const float* Wk = (const float*)d_in[5];
  const float* bk = (const float*)d_in[6];
  const float* Wv = (const float*)d_in[7];
  const float* bv = (const float*)d_in[8];
  const float* Wo = (const float*)d_in[9];
  const float* bo = (const float*)d_in[10];
  float* out = (float*)d_out;
  unsigned short* wsu = (unsigned short*)d_ws;

  k_proj<<<dim3(256, 4), dim3(128), 0, stream>>>(q, k, v, bq, bk, bv, Wq, Wk, Wv, Wo, wsu);
  k_attn<<<dim3(256), dim3(512), 0, stream>>>(wsu, bo, out);
}